// Round 19
// baseline (80.378 us; speedup 1.0000x reference)
//
#include <hip/hip_runtime.h>
#include <math.h>

// ===== 2-dispatch RNNT loss =====
// D1 lsm : log-softmax -> comb (bf16 log2, NONTEMPORAL stores -> clean L3);
//          resets finalize counter.
// D2 dp  : 8 blocks x 1024 threads (one/batch): 16 waves build the <=88
//          parity-compact 4-step weight rows DIRECTLY INTO LDS (comb reads
//          hit clean L3), __syncthreads, wave0 runs the serial quad-step
//          chain from LDS (DPP neighbors, 4-deep static register pipeline);
//          finalize fused via atomic counter.

#define B_DIM  8
#define T_DIM  256
#define U_DIM  100
#define U1_DIM 101
#define V_DIM  128

// comb: diagonal-major packed single-step operands (log2 domain, bf16):
//   cell (d,u) uint32: lo = bl(d-1-u,u), hi = em(d-u,u-1). Row = 512 B.
// No fill: consumers mask validity arithmetically (garbage-safe).
#define ROWU   128
#define DROWS  360
#define NEGF   (-8.0e29f)
#define LOG2E  1.4426950408889634f
#define LN2    0.69314718055994530942f

// LDS V: compact 4-step weight rows. Row = 1280 B (1248 used:
// plane0 V0|V1 @0, plane1 V2|V3 @416, plane2 V4 @832).
#define NITMAX 88
#define VROWB  1280
#define LDS_BYTES (NITMAX * VROWB)    // 112,640 (dynamic; 1 block/CU)

typedef unsigned uv2 __attribute__((ext_vector_type(2)));

__device__ __forceinline__ float ubit(unsigned u) { return __builtin_bit_cast(float, u); }
__device__ __forceinline__ float logadd2(float a, float b) {
    float m = fmaxf(a, b);
    float e = exp2f(-fabsf(a - b));
    return m + log2f(1.0f + e);
}
__device__ __forceinline__ float lse3(float a, float b, float c) {
    float m = fmaxf(fmaxf(a, b), c);
    float s = exp2f(a - m) + exp2f(b - m) + exp2f(c - m);
    return m + log2f(s);
}
__device__ __forceinline__ float lse5(float a, float b, float c, float d, float e) {
    float m = fmaxf(fmaxf(fmaxf(a, b), c), fmaxf(d, e));
    float s = exp2f(a - m) + exp2f(b - m) + exp2f(c - m) + exp2f(d - m) + exp2f(e - m);
    return m + log2f(s);
}
__device__ __forceinline__ float lane_shr1(float x) {
    int r = __builtin_amdgcn_update_dpp(0, __builtin_bit_cast(int, x),
                                        0x138 /*wave_shr:1*/, 0xF, 0xF, true);
    return __builtin_bit_cast(float, r);
}
__device__ __forceinline__ unsigned f2bf(float f) {
    unsigned u = __builtin_bit_cast(unsigned, f);
    u += 0x7FFF + ((u >> 16) & 1);
    return u >> 16;
}

// masked 2-step weights (verified R12-R18)
struct W2 { float tA, mA, lA, tB, mB, lB; };
__device__ __forceinline__ W2 buildW2m(uv2 c0, uv2 cm, int l, int d, int tl, int ul) {
    const int ua = 2 * l, ub = 2 * l + 1;
    float BL0a = ubit(c0.x << 16), EM0a = ubit(c0.x & 0xFFFF0000u);
    float BL0b = ubit(c0.y << 16), EM0b = ubit(c0.y & 0xFFFF0000u);
    float BLma = ubit(cm.x << 16), EMma = ubit(cm.x & 0xFFFF0000u);
    float BLmb = ubit(cm.y << 16), EMmb = ubit(cm.y & 0xFFFF0000u);
    BL0a = (ua <= ul && (unsigned)(d - 1 - ua) <= (unsigned)tl) ? BL0a : NEGF;
    BL0b = (ub <= ul && (unsigned)(d - 1 - ub) <= (unsigned)tl) ? BL0b : NEGF;
    EM0a = (ua >= 1 && ua <= ul && (unsigned)(d - ua) <= (unsigned)tl) ? EM0a : NEGF;
    EM0b = (ub <= ul && (unsigned)(d - ub) <= (unsigned)tl) ? EM0b : NEGF;
    BLma = (ua <= ul && (unsigned)(d - 2 - ua) <= (unsigned)tl) ? BLma : NEGF;
    BLmb = (ub <= ul && (unsigned)(d - 1 - ub) <= (unsigned)tl) ? BLmb : NEGF;
    EMma = (ua >= 1 && ua <= ul && (unsigned)(d - 1 - ua) <= (unsigned)tl) ? EMma : NEGF;
    EMmb = (ub <= ul && (unsigned)(d - 1 - ub) <= (unsigned)tl) ? EMmb : NEGF;
    float BLmp = lane_shr1(BLmb), EMmp = lane_shr1(EMmb);
    W2 w;
    w.tA = BLma + BL0a;
    w.mA = logadd2(EMma + BL0a, BLmp + EM0a);
    w.lA = EMmp + EM0a;
    w.tB = BLmb + BL0b;
    w.mB = logadd2(EMmb + BL0b, BLma + EM0b);
    w.lB = EMma + EM0b;
    if (l == 0) { w.mA = NEGF; w.lA = NEGF; w.lB = NEGF; }
    return w;
}

__device__ __forceinline__ void buildV4(const unsigned* combB, int dt, int l,
                                        int tl, int ul, float* out) {
    const unsigned* C = combB + (size_t)dt * ROWU + 2 * l;
    uv2 c0 = *(const uv2*)(C);
    uv2 c1 = *(const uv2*)(C - ROWU);
    uv2 c2 = *(const uv2*)(C - 2 * ROWU);
    uv2 c3 = *(const uv2*)(C - 3 * ROWU);
    W2 P = buildW2m(c0, c1, l, dt,     tl, ul);
    W2 Q = buildW2m(c2, c3, l, dt - 2, tl, ul);
    float Qt_b1 = lane_shr1(Q.tB), Qm_b1 = lane_shr1(Q.mB), Ql_b1 = lane_shr1(Q.lB);
    float Qt_a1 = lane_shr1(Q.tA), Qm_a1 = lane_shr1(Q.mA), Ql_a1 = lane_shr1(Q.lA);
    out[0] = P.tA + Q.tA;
    out[1] = logadd2(P.tA + Q.mA, P.mA + Qt_b1);
    out[2] = lse3(P.tA + Q.lA, P.mA + Qm_b1, P.lA + Qt_a1);
    out[3] = logadd2(P.mA + Ql_b1, P.lA + Qm_a1);
    out[4] = P.lA + Ql_a1;
    out[5] = P.tB + Q.tB;
    out[6] = logadd2(P.tB + Q.mB, P.mB + Q.tA);
    out[7] = lse3(P.tB + Q.lB, P.mB + Q.mA, P.lB + Qt_b1);
    out[8] = logadd2(P.mB + Q.lA, P.lB + Qm_b1);
    out[9] = P.lB + Ql_b1;
    if (l == 0) { out[1] = NEGF; out[2] = NEGF; out[3] = NEGF; out[4] = NEGF; }
}

__device__ __forceinline__ void prologue(const unsigned* combB, int start, int l,
                                         int tl, int ul, float& v0, float& v1) {
    v0 = (l == 0) ? 0.0f : NEGF;
    v1 = NEGF;
    for (int d = 1; d <= start; ++d) {
        uv2 c = *(const uv2*)(combB + (size_t)d * ROWU + 2 * l);
        const int ua = 2 * l, ub = 2 * l + 1;
        float bl0 = ubit(c.x << 16), em0 = ubit(c.x & 0xFFFF0000u);
        float bl1 = ubit(c.y << 16), em1 = ubit(c.y & 0xFFFF0000u);
        bl0 = (ua <= ul && (unsigned)(d - 1 - ua) <= (unsigned)tl) ? bl0 : NEGF;
        bl1 = (ub <= ul && (unsigned)(d - 1 - ub) <= (unsigned)tl) ? bl1 : NEGF;
        em0 = (ua >= 1 && ua <= ul && (unsigned)(d - ua) <= (unsigned)tl) ? em0 : NEGF;
        em1 = (ub <= ul && (unsigned)(d - ub) <= (unsigned)tl) ? em1 : NEGF;
        float left0 = lane_shr1(v1);
        float a0 = v0 + bl0, p0 = left0 + em0;
        float a1 = v1 + bl1, p1 = v0 + em1;
        v0 = logadd2(a0, p0);
        v1 = logadd2(a1, p1);
    }
}

// D1: log-softmax (log2 domain, bf16 out, NONTEMPORAL comb stores), 32-lane
// half-wave per row, skipping rows with t>tl or u>ul. Resets the counter.
__global__ __launch_bounds__(256) void lsm_kernel(
    const float* __restrict__ acts, const int* __restrict__ labels,
    const int* __restrict__ act_lens, const int* __restrict__ label_lens,
    unsigned short* __restrict__ comb, int* __restrict__ counter, int nrows)
{
    if (blockIdx.x == 0 && threadIdx.x == 0) *counter = 0;

    int rid = blockIdx.x * 8 + (threadIdx.x >> 5);
    if (rid >= nrows) return;
    int hl = threadIdx.x & 31;

    int u  = rid % U1_DIM;
    int bt = rid / U1_DIM;
    int b  = bt / T_DIM;
    int t  = bt - b * T_DIM;
    if (t >= act_lens[b] || u > label_lens[b]) return;   // uniform per half-wave

    const float* row = acts + (size_t)rid * V_DIM;
    float4 x = *reinterpret_cast<const float4*>(row + 4 * hl);
    float4 y = make_float4(x.x * LOG2E, x.y * LOG2E, x.z * LOG2E, x.w * LOG2E);

    float s = exp2f(y.x) + exp2f(y.y) + exp2f(y.z) + exp2f(y.w);
    #pragma unroll
    for (int off = 16; off; off >>= 1) s += __shfl_xor(s, off);
    float lse2 = log2f(s);

    unsigned short* C = comb + (size_t)b * DROWS * (ROWU * 2);
    int d = t + u + 1;
    if (hl == 0)
        __builtin_nontemporal_store((unsigned short)f2bf(y.x - lse2),
                                    &C[(size_t)d * (ROWU * 2) + 2 * u]);
    if (u < U_DIM) {
        int lab = labels[b * U_DIM + u];
        if (hl == (lab >> 2)) {
            int r = lab & 3;
            float v = (r == 0) ? y.x : (r == 1) ? y.y : (r == 2) ? y.z : y.w;
            __builtin_nontemporal_store((unsigned short)f2bf(v - lse2),
                                        &C[(size_t)d * (ROWU * 2) + 2 * u + 3]);
        }
    }
}

// D2: per-batch fused build+chain. 16 waves build the <=88 compact 4-step
// weight rows straight into LDS (comb reads hit clean L3 thanks to D1's nt
// stores); one __syncthreads; wave 0 runs the quad-step chain from LDS.
__global__ __launch_bounds__(1024, 1) void dp_kernel(
    const unsigned* __restrict__ comb,
    const int* __restrict__ act_lens, const int* __restrict__ label_lens,
    float* __restrict__ loglike, int* __restrict__ counter,
    float* __restrict__ out)
{
    extern __shared__ char sV[];                // NITMAX * 1280 B

    const int b = blockIdx.x;
    const int l = threadIdx.x & 63;
    const int w = threadIdx.x >> 6;             // 16 waves
    const int tl    = act_lens[b] - 1;
    const int ul    = label_lens[b];
    const int dfin  = tl + ul;                  // [177, 355]
    const int start = dfin & 3;
    const int niter = dfin >> 2;                // 44..88 composed steps

    const unsigned* combB = comb + (size_t)b * DROWS * ROWU;

    // ---- build 4-step weight rows into LDS (16 waves partition) ----
    for (int it = w; it < niter; it += 16) {
        int dt = start + 4 * (it + 1);          // <= dfin
        float o[10];
        buildV4(combB, dt, l, tl, ul, o);
        if (l < 52) {
            char* ro = sV + (size_t)it * VROWB + 8 * l;
            uv2 p0, p1, p2;
            p0.x = f2bf(o[0]) | (f2bf(o[1]) << 16); p0.y = f2bf(o[5]) | (f2bf(o[6]) << 16);
            p1.x = f2bf(o[2]) | (f2bf(o[3]) << 16); p1.y = f2bf(o[7]) | (f2bf(o[8]) << 16);
            p2.x = f2bf(o[4]);                      p2.y = f2bf(o[9]);
            *(uv2*)(ro)       = p0;
            *(uv2*)(ro + 416) = p1;
            *(uv2*)(ro + 832) = p2;
        }
    }
    __syncthreads();
    if (w != 0) return;

    // ---- serial quad-step chain (wave 0), LDS-only operands ----
    float fin_bl = ubit(combB[(size_t)(dfin + 1) * ROWU + ul] << 16);
    float v0, v1;
    prologue(combB, start, l, tl, ul, v0, v1);
    float rf0 = NEGF, rf1 = NEGF;

    const char* Lc = sV + 8 * l;
    uv2 q0[4], q1[4], q2[4];
    #pragma unroll
    for (int j = 0; j < 4; ++j) {               // prime rows 0..3
        const char* p = Lc + (size_t)j * VROWB;
        q0[j] = *(const uv2*)(p);
        q1[j] = *(const uv2*)(p + 416);
        q2[j] = *(const uv2*)(p + 832);
    }
    const int ngroups = (niter + 3) >> 2;       // 11..22 groups of 4
    for (int g4 = 0; g4 < ngroups; ++g4) {
        const int it0 = g4 * 4;
        #pragma unroll
        for (int J = 0; J < 4; ++J) {           // static slot index (rule #20)
            const int it = it0 + J;
            uv2 a0 = q0[J], a1 = q1[J], a2 = q2[J];
            float V0a = ubit(a0.x << 16), V1a = ubit(a0.x & 0xFFFF0000u);
            float V0b = ubit(a0.y << 16), V1b = ubit(a0.y & 0xFFFF0000u);
            float V2a = ubit(a1.x << 16), V3a = ubit(a1.x & 0xFFFF0000u);
            float V2b = ubit(a1.y << 16), V3b = ubit(a1.y & 0xFFFF0000u);
            float V4a = ubit(a2.x << 16), V4b = ubit(a2.y << 16);
            float s1 = lane_shr1(v1);           // alpha[2l-1]
            float s0 = lane_shr1(v0);           // alpha[2l-2]
            float s3 = lane_shr1(s1);           // alpha[2l-3]
            float s2 = lane_shr1(s0);           // alpha[2l-4]
            float nA = lse5(v0 + V0a, s1 + V1a, s0 + V2a, s3 + V3a, s2 + V4a);
            float nB = lse5(v1 + V0b, v0 + V1b, s1 + V2b, s0 + V3b, s3 + V4b);
            if (it == niter - 1) { rf0 = nA; rf1 = nB; }   // capture at dfin
            v0 = nA; v1 = nB;
            int rr = it + 4; rr = rr < niter ? rr : niter - 1;   // staged-safe
            const char* p = Lc + (size_t)rr * VROWB;
            q0[J] = *(const uv2*)(p);
            q1[J] = *(const uv2*)(p + 416);
            q2[J] = *(const uv2*)(p + 832);
        }
    }

    float res = (ul & 1) ? rf1 : rf0;           // alpha[tl,ul] in lane ul>>1
    if (l == (ul >> 1)) {
        loglike[b] = LN2 * (res + fin_bl);
        __threadfence();                        // publish before signaling
        int old = atomicAdd(counter, 1);        // device-scope
        if (old == B_DIM - 1) {                 // last block finalizes
            __threadfence();
            float s = 0.0f;
            #pragma unroll
            for (int i = 0; i < B_DIM; ++i)
                s += __hip_atomic_load(&loglike[i], __ATOMIC_RELAXED,
                                       __HIP_MEMORY_SCOPE_AGENT);
            out[0] = -s / (float)B_DIM;
        }
    }
}

extern "C" void kernel_launch(void* const* d_in, const int* in_sizes, int n_in,
                              void* d_out, int out_size, void* d_ws, size_t ws_size,
                              hipStream_t stream) {
    const float* acts       = (const float*)d_in[0];
    const int*   labels     = (const int*)d_in[1];
    const int*   act_lens   = (const int*)d_in[2];
    const int*   label_lens = (const int*)d_in[3];

    unsigned* comb    = (unsigned*)d_ws;                          // 1.47 MB
    float*    loglike = (float*)(comb + (size_t)B_DIM * DROWS * ROWU);
    int*      counter = (int*)(loglike + B_DIM);

    int nrows   = B_DIM * T_DIM * U1_DIM;                         // 206,848
    int nblocks = (nrows + 7) / 8;

    // >64KB dynamic LDS (112,640 B; CU has 160 KB) — capture-safe (R12/R18 proven)
    hipFuncSetAttribute(reinterpret_cast<const void*>(dp_kernel),
                        hipFuncAttributeMaxDynamicSharedMemorySize, LDS_BYTES);

    lsm_kernel<<<nblocks, 256, 0, stream>>>(acts, labels, act_lens, label_lens,
                                            (unsigned short*)comb, counter, nrows);
    dp_kernel<<<B_DIM, 1024, LDS_BYTES, stream>>>(comb, act_lens, label_lens,
                                                  loglike, counter, (float*)d_out);
}

// Round 20
// 58.972 us; speedup vs baseline: 1.3630x; 1.3630x over previous
//
#include <hip/hip_runtime.h>
#include <math.h>

// ===== 2-dispatch RNNT loss =====
// D1 lsm : log-softmax -> comb (bf16 log2, REGULAR stores); resets counter.
// D2 dp  : 8 blocks x 1024 threads (one/batch). 16 waves build the <=88
//          parity-compact 4-step weight rows into LDS with ISSUE-ALL-THEN-
//          WAIT asm-pinned comb loads (one exposed latency per wave, not
//          six). __syncthreads; wave0 runs the serial quad-step chain from
//          LDS (DPP neighbors, 4-deep static register pipeline); finalize
//          fused via atomic counter.

#define B_DIM  8
#define T_DIM  256
#define U_DIM  100
#define U1_DIM 101
#define V_DIM  128

// comb: diagonal-major packed single-step operands (log2 domain, bf16):
//   cell (d,u) uint32: lo = bl(d-1-u,u), hi = em(d-u,u-1). Row = 512 B.
// No fill: consumers mask validity arithmetically (garbage-safe).
#define ROWU   128
#define DROWS  360
#define NEGF   (-8.0e29f)
#define LOG2E  1.4426950408889634f
#define LN2    0.69314718055994530942f

// LDS V: compact 4-step weight rows. Row = 1280 B
// (plane0 V0|V1 @0, plane1 V2|V3 @416, plane2 V4 @832).
#define NITMAX 88
#define VROWB  1280
#define LDS_BYTES (NITMAX * VROWB)    // 112,640 (dynamic; 1 block/CU)
#define RPW    6                      // rows per wave: ceil(88/16)

typedef unsigned uv2 __attribute__((ext_vector_type(2)));

__device__ __forceinline__ float ubit(unsigned u) { return __builtin_bit_cast(float, u); }
__device__ __forceinline__ float logadd2(float a, float b) {
    float m = fmaxf(a, b);
    float e = exp2f(-fabsf(a - b));
    return m + log2f(1.0f + e);
}
__device__ __forceinline__ float lse3(float a, float b, float c) {
    float m = fmaxf(fmaxf(a, b), c);
    float s = exp2f(a - m) + exp2f(b - m) + exp2f(c - m);
    return m + log2f(s);
}
__device__ __forceinline__ float lse5(float a, float b, float c, float d, float e) {
    float m = fmaxf(fmaxf(fmaxf(a, b), c), fmaxf(d, e));
    float s = exp2f(a - m) + exp2f(b - m) + exp2f(c - m) + exp2f(d - m) + exp2f(e - m);
    return m + log2f(s);
}
__device__ __forceinline__ float lane_shr1(float x) {
    int r = __builtin_amdgcn_update_dpp(0, __builtin_bit_cast(int, x),
                                        0x138 /*wave_shr:1*/, 0xF, 0xF, true);
    return __builtin_bit_cast(float, r);
}
__device__ __forceinline__ unsigned f2bf(float f) {
    unsigned u = __builtin_bit_cast(unsigned, f);
    u += 0x7FFF + ((u >> 16) & 1);
    return u >> 16;
}

// masked 2-step weights (verified R12-R18)
struct W2 { float tA, mA, lA, tB, mB, lB; };
__device__ __forceinline__ W2 buildW2m(uv2 c0, uv2 cm, int l, int d, int tl, int ul) {
    const int ua = 2 * l, ub = 2 * l + 1;
    float BL0a = ubit(c0.x << 16), EM0a = ubit(c0.x & 0xFFFF0000u);
    float BL0b = ubit(c0.y << 16), EM0b = ubit(c0.y & 0xFFFF0000u);
    float BLma = ubit(cm.x << 16), EMma = ubit(cm.x & 0xFFFF0000u);
    float BLmb = ubit(cm.y << 16), EMmb = ubit(cm.y & 0xFFFF0000u);
    BL0a = (ua <= ul && (unsigned)(d - 1 - ua) <= (unsigned)tl) ? BL0a : NEGF;
    BL0b = (ub <= ul && (unsigned)(d - 1 - ub) <= (unsigned)tl) ? BL0b : NEGF;
    EM0a = (ua >= 1 && ua <= ul && (unsigned)(d - ua) <= (unsigned)tl) ? EM0a : NEGF;
    EM0b = (ub <= ul && (unsigned)(d - ub) <= (unsigned)tl) ? EM0b : NEGF;
    BLma = (ua <= ul && (unsigned)(d - 2 - ua) <= (unsigned)tl) ? BLma : NEGF;
    BLmb = (ub <= ul && (unsigned)(d - 1 - ub) <= (unsigned)tl) ? BLmb : NEGF;
    EMma = (ua >= 1 && ua <= ul && (unsigned)(d - 1 - ua) <= (unsigned)tl) ? EMma : NEGF;
    EMmb = (ub <= ul && (unsigned)(d - 1 - ub) <= (unsigned)tl) ? EMmb : NEGF;
    float BLmp = lane_shr1(BLmb), EMmp = lane_shr1(EMmb);
    W2 w;
    w.tA = BLma + BL0a;
    w.mA = logadd2(EMma + BL0a, BLmp + EM0a);
    w.lA = EMmp + EM0a;
    w.tB = BLmb + BL0b;
    w.mB = logadd2(EMmb + BL0b, BLma + EM0b);
    w.lB = EMma + EM0b;
    if (l == 0) { w.mA = NEGF; w.lA = NEGF; w.lB = NEGF; }
    return w;
}

// register-input 4-step weight build (same algebra as verified buildV4)
__device__ __forceinline__ void buildV4reg(uv2 c0, uv2 c1, uv2 c2, uv2 c3,
                                           int dt, int l, int tl, int ul,
                                           float* out) {
    W2 P = buildW2m(c0, c1, l, dt,     tl, ul);
    W2 Q = buildW2m(c2, c3, l, dt - 2, tl, ul);
    float Qt_b1 = lane_shr1(Q.tB), Qm_b1 = lane_shr1(Q.mB), Ql_b1 = lane_shr1(Q.lB);
    float Qt_a1 = lane_shr1(Q.tA), Qm_a1 = lane_shr1(Q.mA), Ql_a1 = lane_shr1(Q.lA);
    out[0] = P.tA + Q.tA;
    out[1] = logadd2(P.tA + Q.mA, P.mA + Qt_b1);
    out[2] = lse3(P.tA + Q.lA, P.mA + Qm_b1, P.lA + Qt_a1);
    out[3] = logadd2(P.mA + Ql_b1, P.lA + Qm_a1);
    out[4] = P.lA + Ql_a1;
    out[5] = P.tB + Q.tB;
    out[6] = logadd2(P.tB + Q.mB, P.mB + Q.tA);
    out[7] = lse3(P.tB + Q.lB, P.mB + Q.mA, P.lB + Qt_b1);
    out[8] = logadd2(P.mB + Q.lA, P.lB + Qm_b1);
    out[9] = P.lB + Ql_b1;
    if (l == 0) { out[1] = NEGF; out[2] = NEGF; out[3] = NEGF; out[4] = NEGF; }
}

__device__ __forceinline__ void prologue(const unsigned* combB, int start, int l,
                                         int tl, int ul, float& v0, float& v1) {
    v0 = (l == 0) ? 0.0f : NEGF;
    v1 = NEGF;
    for (int d = 1; d <= start; ++d) {
        uv2 c = *(const uv2*)(combB + (size_t)d * ROWU + 2 * l);
        const int ua = 2 * l, ub = 2 * l + 1;
        float bl0 = ubit(c.x << 16), em0 = ubit(c.x & 0xFFFF0000u);
        float bl1 = ubit(c.y << 16), em1 = ubit(c.y & 0xFFFF0000u);
        bl0 = (ua <= ul && (unsigned)(d - 1 - ua) <= (unsigned)tl) ? bl0 : NEGF;
        bl1 = (ub <= ul && (unsigned)(d - 1 - ub) <= (unsigned)tl) ? bl1 : NEGF;
        em0 = (ua >= 1 && ua <= ul && (unsigned)(d - ua) <= (unsigned)tl) ? em0 : NEGF;
        em1 = (ub <= ul && (unsigned)(d - ub) <= (unsigned)tl) ? em1 : NEGF;
        float left0 = lane_shr1(v1);
        float a0 = v0 + bl0, p0 = left0 + em0;
        float a1 = v1 + bl1, p1 = v0 + em1;
        v0 = logadd2(a0, p0);
        v1 = logadd2(a1, p1);
    }
}

// D1: log-softmax (log2 domain, bf16 out, REGULAR stores), 32-lane half-wave
// per row, skipping rows with t>tl or u>ul. Resets the finalize counter.
__global__ __launch_bounds__(256) void lsm_kernel(
    const float* __restrict__ acts, const int* __restrict__ labels,
    const int* __restrict__ act_lens, const int* __restrict__ label_lens,
    unsigned short* __restrict__ comb, int* __restrict__ counter, int nrows)
{
    if (blockIdx.x == 0 && threadIdx.x == 0) *counter = 0;

    int rid = blockIdx.x * 8 + (threadIdx.x >> 5);
    if (rid >= nrows) return;
    int hl = threadIdx.x & 31;

    int u  = rid % U1_DIM;
    int bt = rid / U1_DIM;
    int b  = bt / T_DIM;
    int t  = bt - b * T_DIM;
    if (t >= act_lens[b] || u > label_lens[b]) return;   // uniform per half-wave

    const float* row = acts + (size_t)rid * V_DIM;
    float4 x = *reinterpret_cast<const float4*>(row + 4 * hl);
    float4 y = make_float4(x.x * LOG2E, x.y * LOG2E, x.z * LOG2E, x.w * LOG2E);

    float s = exp2f(y.x) + exp2f(y.y) + exp2f(y.z) + exp2f(y.w);
    #pragma unroll
    for (int off = 16; off; off >>= 1) s += __shfl_xor(s, off);
    float lse2 = log2f(s);

    unsigned short* C = comb + (size_t)b * DROWS * (ROWU * 2);
    int d = t + u + 1;
    if (hl == 0)
        C[(size_t)d * (ROWU * 2) + 2 * u] = (unsigned short)f2bf(y.x - lse2);
    if (u < U_DIM) {
        int lab = labels[b * U_DIM + u];
        if (hl == (lab >> 2)) {
            int r = lab & 3;
            float v = (r == 0) ? y.x : (r == 1) ? y.y : (r == 2) ? y.z : y.w;
            C[(size_t)d * (ROWU * 2) + 2 * u + 3] = (unsigned short)f2bf(v - lse2);
        }
    }
}

// D2: per-batch fused build+chain. Each of 16 waves owns rows {w, w+16, ...}
// (clamped; duplicate writes of identical data are benign). ISSUE all 24
// comb loads (asm-pinned), ONE vmcnt(0), compute all rows -> LDS.
// __syncthreads; wave0 runs the quad-step chain from LDS.
__global__ __launch_bounds__(1024, 1) void dp_kernel(
    const unsigned* __restrict__ comb,
    const int* __restrict__ act_lens, const int* __restrict__ label_lens,
    float* __restrict__ loglike, int* __restrict__ counter,
    float* __restrict__ out)
{
    extern __shared__ char sV[];                // NITMAX * 1280 B

    const int b = blockIdx.x;
    const int l = threadIdx.x & 63;
    const int w = threadIdx.x >> 6;             // 16 waves
    const int tl    = act_lens[b] - 1;
    const int ul    = label_lens[b];
    const int dfin  = tl + ul;                  // [177, 355]
    const int start = dfin & 3;
    const int niter = dfin >> 2;                // 44..88 composed steps

    const unsigned* combB = comb + (size_t)b * DROWS * ROWU;

    // ---- Phase A: issue-all-then-wait build (16 waves) ----
    {
        int itc[RPW], dtv[RPW];
        uv2 c0[RPW], c1[RPW], c2[RPW], c3[RPW];
        #pragma unroll
        for (int j = 0; j < RPW; ++j) {
            int it = w + 16 * j;
            itc[j] = it < niter ? it : niter - 1;        // clamp (benign dup)
            dtv[j] = start + 4 * (itc[j] + 1);           // <= dfin
            const unsigned* p = combB + (size_t)dtv[j] * ROWU + 2 * l;
            asm volatile("global_load_dwordx2 %0, %1, off" : "=v"(c0[j]) : "v"(p));
            asm volatile("global_load_dwordx2 %0, %1, off" : "=v"(c1[j]) : "v"(p - ROWU));
            asm volatile("global_load_dwordx2 %0, %1, off" : "=v"(c2[j]) : "v"(p - 2 * ROWU));
            asm volatile("global_load_dwordx2 %0, %1, off" : "=v"(c3[j]) : "v"(p - 3 * ROWU));
        }
        asm volatile("s_waitcnt vmcnt(0)" ::: "memory");  // one exposed latency
        __builtin_amdgcn_sched_barrier(0);                // rule #18: pin uses after wait
        #pragma unroll
        for (int j = 0; j < RPW; ++j) {
            float o[10];
            buildV4reg(c0[j], c1[j], c2[j], c3[j], dtv[j], l, tl, ul, o);
            if (l < 52) {
                char* ro = sV + (size_t)itc[j] * VROWB + 8 * l;
                uv2 p0, p1, p2;
                p0.x = f2bf(o[0]) | (f2bf(o[1]) << 16); p0.y = f2bf(o[5]) | (f2bf(o[6]) << 16);
                p1.x = f2bf(o[2]) | (f2bf(o[3]) << 16); p1.y = f2bf(o[7]) | (f2bf(o[8]) << 16);
                p2.x = f2bf(o[4]);                      p2.y = f2bf(o[9]);
                *(uv2*)(ro)       = p0;
                *(uv2*)(ro + 416) = p1;
                *(uv2*)(ro + 832) = p2;
            }
        }
    }
    __syncthreads();
    if (w != 0) return;

    // ---- Phase B: serial quad-step chain (wave 0), LDS-only operands ----
    float fin_bl = ubit(combB[(size_t)(dfin + 1) * ROWU + ul] << 16);
    float v0, v1;
    prologue(combB, start, l, tl, ul, v0, v1);
    float rf0 = NEGF, rf1 = NEGF;

    const char* Lc = sV + 8 * l;
    uv2 q0[4], q1[4], q2[4];
    #pragma unroll
    for (int j = 0; j < 4; ++j) {               // prime rows 0..3
        const char* p = Lc + (size_t)j * VROWB;
        q0[j] = *(const uv2*)(p);
        q1[j] = *(const uv2*)(p + 416);
        q2[j] = *(const uv2*)(p + 832);
    }
    const int ngroups = (niter + 3) >> 2;       // 11..22 groups of 4
    for (int g4 = 0; g4 < ngroups; ++g4) {
        const int it0 = g4 * 4;
        #pragma unroll
        for (int J = 0; J < 4; ++J) {           // static slot index (rule #20)
            const int it = it0 + J;
            uv2 a0 = q0[J], a1 = q1[J], a2 = q2[J];
            float V0a = ubit(a0.x << 16), V1a = ubit(a0.x & 0xFFFF0000u);
            float V0b = ubit(a0.y << 16), V1b = ubit(a0.y & 0xFFFF0000u);
            float V2a = ubit(a1.x << 16), V3a = ubit(a1.x & 0xFFFF0000u);
            float V2b = ubit(a1.y << 16), V3b = ubit(a1.y & 0xFFFF0000u);
            float V4a = ubit(a2.x << 16), V4b = ubit(a2.y << 16);
            float s1 = lane_shr1(v1);           // alpha[2l-1]
            float s0 = lane_shr1(v0);           // alpha[2l-2]
            float s3 = lane_shr1(s1);           // alpha[2l-3]
            float s2 = lane_shr1(s0);           // alpha[2l-4]
            float nA = lse5(v0 + V0a, s1 + V1a, s0 + V2a, s3 + V3a, s2 + V4a);
            float nB = lse5(v1 + V0b, v0 + V1b, s1 + V2b, s0 + V3b, s3 + V4b);
            if (it == niter - 1) { rf0 = nA; rf1 = nB; }   // capture at dfin
            v0 = nA; v1 = nB;
            int rr = it + 4; rr = rr < niter ? rr : niter - 1;   // staged-safe
            const char* p = Lc + (size_t)rr * VROWB;
            q0[J] = *(const uv2*)(p);
            q1[J] = *(const uv2*)(p + 416);
            q2[J] = *(const uv2*)(p + 832);
        }
    }

    float res = (ul & 1) ? rf1 : rf0;           // alpha[tl,ul] in lane ul>>1
    if (l == (ul >> 1)) {
        loglike[b] = LN2 * (res + fin_bl);
        __threadfence();                        // publish before signaling
        int old = atomicAdd(counter, 1);        // device-scope
        if (old == B_DIM - 1) {                 // last block finalizes
            __threadfence();
            float s = 0.0f;
            #pragma unroll
            for (int i = 0; i < B_DIM; ++i)
                s += __hip_atomic_load(&loglike[i], __ATOMIC_RELAXED,
                                       __HIP_MEMORY_SCOPE_AGENT);
            out[0] = -s / (float)B_DIM;
        }
    }
}

extern "C" void kernel_launch(void* const* d_in, const int* in_sizes, int n_in,
                              void* d_out, int out_size, void* d_ws, size_t ws_size,
                              hipStream_t stream) {
    const float* acts       = (const float*)d_in[0];
    const int*   labels     = (const int*)d_in[1];
    const int*   act_lens   = (const int*)d_in[2];
    const int*   label_lens = (const int*)d_in[3];

    unsigned* comb    = (unsigned*)d_ws;                          // 1.47 MB
    float*    loglike = (float*)(comb + (size_t)B_DIM * DROWS * ROWU);
    int*      counter = (int*)(loglike + B_DIM);

    int nrows   = B_DIM * T_DIM * U1_DIM;                         // 206,848
    int nblocks = (nrows + 7) / 8;

    // >64KB dynamic LDS (112,640 B; CU has 160 KB) — capture-safe (R12/R18 proven)
    hipFuncSetAttribute(reinterpret_cast<const void*>(dp_kernel),
                        hipFuncAttributeMaxDynamicSharedMemorySize, LDS_BYTES);

    lsm_kernel<<<nblocks, 256, 0, stream>>>(acts, labels, act_lens, label_lens,
                                            (unsigned short*)comb, counter, nrows);
    dp_kernel<<<B_DIM, 1024, LDS_BYTES, stream>>>(comb, act_lens, label_lens,
                                                  loglike, counter, (float*)d_out);
}

// Round 21
// 49.276 us; speedup vs baseline: 1.6312x; 1.1968x over previous
//
#include <hip/hip_runtime.h>
#include <math.h>

// ===== 3-dispatch RNNT loss (R18 — session best: 49.8 us) =====
// D1 lsm : log-softmax -> comb (bf16, log2 domain); resets finalize counter.
// D2 v4c : grid-parallel parity-compact 4-step weight build, nt stores.
// D3 dp3 : per-batch: bulk-stage compact V into LDS (global_load_lds burst,
//          one drain), then serial quad-step chain purely from LDS (DPP
//          neighbors, 4-deep static register pipeline). Finalize fused.

#define B_DIM  8
#define T_DIM  256
#define U_DIM  100
#define U1_DIM 101
#define V_DIM  128

// comb: diagonal-major packed single-step operands (log2 domain, bf16):
//   cell (d,u) uint32: lo = bl(d-1-u,u), hi = em(d-u,u-1). Row = 512 B.
// No fill: consumers mask validity arithmetically (garbage-safe).
#define ROWU   128
#define DROWS  360
#define NEGF   (-8.0e29f)
#define LOG2E  1.4426950408889634f
#define LN2    0.69314718055994530942f

// V: per-batch COMPACT 4-step weight rows (row it <=> diagonal start+4(it+1)).
// Row = 320 uints = 1280 B (312 used: V0|V1 @0, V2|V3 @104, V4 @208).
#define NITMAX 88
#define VROWU  320
#define VROWB  1280
#define LDS_BYTES (NITMAX * VROWB)    // 112,640 (dynamic; 1 block/CU)

typedef unsigned uv2 __attribute__((ext_vector_type(2)));

__device__ __forceinline__ float ubit(unsigned u) { return __builtin_bit_cast(float, u); }
__device__ __forceinline__ float logadd2(float a, float b) {
    float m = fmaxf(a, b);
    float e = exp2f(-fabsf(a - b));
    return m + log2f(1.0f + e);
}
__device__ __forceinline__ float lse3(float a, float b, float c) {
    float m = fmaxf(fmaxf(a, b), c);
    float s = exp2f(a - m) + exp2f(b - m) + exp2f(c - m);
    return m + log2f(s);
}
__device__ __forceinline__ float lse5(float a, float b, float c, float d, float e) {
    float m = fmaxf(fmaxf(fmaxf(a, b), c), fmaxf(d, e));
    float s = exp2f(a - m) + exp2f(b - m) + exp2f(c - m) + exp2f(d - m) + exp2f(e - m);
    return m + log2f(s);
}
__device__ __forceinline__ float lane_shr1(float x) {
    int r = __builtin_amdgcn_update_dpp(0, __builtin_bit_cast(int, x),
                                        0x138 /*wave_shr:1*/, 0xF, 0xF, true);
    return __builtin_bit_cast(float, r);
}
__device__ __forceinline__ unsigned f2bf(float f) {
    unsigned u = __builtin_bit_cast(unsigned, f);
    u += 0x7FFF + ((u >> 16) & 1);
    return u >> 16;
}

// masked 2-step weights (verified R12-R18)
struct W2 { float tA, mA, lA, tB, mB, lB; };
__device__ __forceinline__ W2 buildW2m(uv2 c0, uv2 cm, int l, int d, int tl, int ul) {
    const int ua = 2 * l, ub = 2 * l + 1;
    float BL0a = ubit(c0.x << 16), EM0a = ubit(c0.x & 0xFFFF0000u);
    float BL0b = ubit(c0.y << 16), EM0b = ubit(c0.y & 0xFFFF0000u);
    float BLma = ubit(cm.x << 16), EMma = ubit(cm.x & 0xFFFF0000u);
    float BLmb = ubit(cm.y << 16), EMmb = ubit(cm.y & 0xFFFF0000u);
    BL0a = (ua <= ul && (unsigned)(d - 1 - ua) <= (unsigned)tl) ? BL0a : NEGF;
    BL0b = (ub <= ul && (unsigned)(d - 1 - ub) <= (unsigned)tl) ? BL0b : NEGF;
    EM0a = (ua >= 1 && ua <= ul && (unsigned)(d - ua) <= (unsigned)tl) ? EM0a : NEGF;
    EM0b = (ub <= ul && (unsigned)(d - ub) <= (unsigned)tl) ? EM0b : NEGF;
    BLma = (ua <= ul && (unsigned)(d - 2 - ua) <= (unsigned)tl) ? BLma : NEGF;
    BLmb = (ub <= ul && (unsigned)(d - 1 - ub) <= (unsigned)tl) ? BLmb : NEGF;
    EMma = (ua >= 1 && ua <= ul && (unsigned)(d - 1 - ua) <= (unsigned)tl) ? EMma : NEGF;
    EMmb = (ub <= ul && (unsigned)(d - 1 - ub) <= (unsigned)tl) ? EMmb : NEGF;
    float BLmp = lane_shr1(BLmb), EMmp = lane_shr1(EMmb);
    W2 w;
    w.tA = BLma + BL0a;
    w.mA = logadd2(EMma + BL0a, BLmp + EM0a);
    w.lA = EMmp + EM0a;
    w.tB = BLmb + BL0b;
    w.mB = logadd2(EMmb + BL0b, BLma + EM0b);
    w.lB = EMma + EM0b;
    if (l == 0) { w.mA = NEGF; w.lA = NEGF; w.lB = NEGF; }
    return w;
}

__device__ __forceinline__ void buildV4(const unsigned* combB, int dt, int l,
                                        int tl, int ul, float* out) {
    const unsigned* C = combB + (size_t)dt * ROWU + 2 * l;
    uv2 c0 = *(const uv2*)(C);
    uv2 c1 = *(const uv2*)(C - ROWU);
    uv2 c2 = *(const uv2*)(C - 2 * ROWU);
    uv2 c3 = *(const uv2*)(C - 3 * ROWU);
    W2 P = buildW2m(c0, c1, l, dt,     tl, ul);
    W2 Q = buildW2m(c2, c3, l, dt - 2, tl, ul);
    float Qt_b1 = lane_shr1(Q.tB), Qm_b1 = lane_shr1(Q.mB), Ql_b1 = lane_shr1(Q.lB);
    float Qt_a1 = lane_shr1(Q.tA), Qm_a1 = lane_shr1(Q.mA), Ql_a1 = lane_shr1(Q.lA);
    out[0] = P.tA + Q.tA;
    out[1] = logadd2(P.tA + Q.mA, P.mA + Qt_b1);
    out[2] = lse3(P.tA + Q.lA, P.mA + Qm_b1, P.lA + Qt_a1);
    out[3] = logadd2(P.mA + Ql_b1, P.lA + Qm_a1);
    out[4] = P.lA + Ql_a1;
    out[5] = P.tB + Q.tB;
    out[6] = logadd2(P.tB + Q.mB, P.mB + Q.tA);
    out[7] = lse3(P.tB + Q.lB, P.mB + Q.mA, P.lB + Qt_b1);
    out[8] = logadd2(P.mB + Q.lA, P.lB + Qm_b1);
    out[9] = P.lB + Ql_b1;
    if (l == 0) { out[1] = NEGF; out[2] = NEGF; out[3] = NEGF; out[4] = NEGF; }
}

__device__ __forceinline__ void prologue(const unsigned* combB, int start, int l,
                                         int tl, int ul, float& v0, float& v1) {
    v0 = (l == 0) ? 0.0f : NEGF;
    v1 = NEGF;
    for (int d = 1; d <= start; ++d) {
        uv2 c = *(const uv2*)(combB + (size_t)d * ROWU + 2 * l);
        const int ua = 2 * l, ub = 2 * l + 1;
        float bl0 = ubit(c.x << 16), em0 = ubit(c.x & 0xFFFF0000u);
        float bl1 = ubit(c.y << 16), em1 = ubit(c.y & 0xFFFF0000u);
        bl0 = (ua <= ul && (unsigned)(d - 1 - ua) <= (unsigned)tl) ? bl0 : NEGF;
        bl1 = (ub <= ul && (unsigned)(d - 1 - ub) <= (unsigned)tl) ? bl1 : NEGF;
        em0 = (ua >= 1 && ua <= ul && (unsigned)(d - ua) <= (unsigned)tl) ? em0 : NEGF;
        em1 = (ub <= ul && (unsigned)(d - ub) <= (unsigned)tl) ? em1 : NEGF;
        float left0 = lane_shr1(v1);
        float a0 = v0 + bl0, p0 = left0 + em0;
        float a1 = v1 + bl1, p1 = v0 + em1;
        v0 = logadd2(a0, p0);
        v1 = logadd2(a1, p1);
    }
}

// D1: log-softmax (log2 domain, bf16 out), 32-lane half-wave per row,
// skipping rows with t>tl or u>ul. Also resets the finalize counter.
__global__ __launch_bounds__(256) void lsm_kernel(
    const float* __restrict__ acts, const int* __restrict__ labels,
    const int* __restrict__ act_lens, const int* __restrict__ label_lens,
    unsigned short* __restrict__ comb, int* __restrict__ counter, int nrows)
{
    if (blockIdx.x == 0 && threadIdx.x == 0) *counter = 0;

    int rid = blockIdx.x * 8 + (threadIdx.x >> 5);
    if (rid >= nrows) return;
    int hl = threadIdx.x & 31;

    int u  = rid % U1_DIM;
    int bt = rid / U1_DIM;
    int b  = bt / T_DIM;
    int t  = bt - b * T_DIM;
    if (t >= act_lens[b] || u > label_lens[b]) return;   // uniform per half-wave

    const float* row = acts + (size_t)rid * V_DIM;
    float4 x = *reinterpret_cast<const float4*>(row + 4 * hl);
    float4 y = make_float4(x.x * LOG2E, x.y * LOG2E, x.z * LOG2E, x.w * LOG2E);

    float s = exp2f(y.x) + exp2f(y.y) + exp2f(y.z) + exp2f(y.w);
    #pragma unroll
    for (int off = 16; off; off >>= 1) s += __shfl_xor(s, off);
    float lse2 = log2f(s);

    unsigned short* C = comb + (size_t)b * DROWS * (ROWU * 2);
    int d = t + u + 1;
    if (hl == 0)
        C[(size_t)d * (ROWU * 2) + 2 * u] = (unsigned short)f2bf(y.x - lse2);
    if (u < U_DIM) {
        int lab = labels[b * U_DIM + u];
        if (hl == (lab >> 2)) {
            int r = lab & 3;
            float v = (r == 0) ? y.x : (r == 1) ? y.y : (r == 2) ? y.z : y.w;
            C[(size_t)d * (ROWU * 2) + 2 * u + 3] = (unsigned short)f2bf(v - lse2);
        }
    }
}

// D2: parity-compact grid-parallel V4 build (nt stores -> clean in L3).
__global__ __launch_bounds__(256) void v4c_kernel(
    const unsigned* __restrict__ comb,
    const int* __restrict__ act_lens, const int* __restrict__ label_lens,
    unsigned* __restrict__ V)
{
    int wid = blockIdx.x * 4 + (threadIdx.x >> 6);   // 0 .. B_DIM*NITMAX-1
    if (wid >= B_DIM * NITMAX) return;
    int l  = threadIdx.x & 63;
    int b  = wid / NITMAX;
    int it = wid - b * NITMAX;

    int tl = act_lens[b] - 1, ul = label_lens[b];
    int dfin = tl + ul, start = dfin & 3, niter = dfin >> 2;
    if (it >= niter) return;                         // compact: only needed rows
    int dt = start + 4 * (it + 1);                   // <= dfin

    float o[10];
    buildV4(comb + (size_t)b * DROWS * ROWU, dt, l, tl, ul, o);

    if (l < 52) {
        unsigned* ro = V + (size_t)(b * NITMAX + it) * VROWU;
        uv2 p0, p1, p2;
        p0.x = f2bf(o[0]) | (f2bf(o[1]) << 16); p0.y = f2bf(o[5]) | (f2bf(o[6]) << 16);
        p1.x = f2bf(o[2]) | (f2bf(o[3]) << 16); p1.y = f2bf(o[7]) | (f2bf(o[8]) << 16);
        p2.x = f2bf(o[4]);                      p2.y = f2bf(o[9]);
        __builtin_nontemporal_store(p0, (uv2*)(ro + 2 * l));
        __builtin_nontemporal_store(p1, (uv2*)(ro + 104 + 2 * l));
        __builtin_nontemporal_store(p2, (uv2*)(ro + 208 + 2 * l));
    }
}

// D3: per-batch chain. Stage compact V (niter rows, <=112,640 B) into LDS
// with a global_load_lds burst + one drain; run the quad-step chain from LDS
// (3x ds_read_b64/iter, 4-deep statically-indexed register pipeline, DPP
// neighbors -- no lgkm interaction). Finalize fused via atomic counter.
__global__ __launch_bounds__(64, 1) void dp3_kernel(
    const unsigned* __restrict__ comb, const unsigned* __restrict__ V,
    const int* __restrict__ act_lens, const int* __restrict__ label_lens,
    float* __restrict__ loglike, int* __restrict__ counter,
    float* __restrict__ out)
{
    extern __shared__ char sV[];                // NITMAX * 1280 B

    const int b = blockIdx.x;
    const int l = threadIdx.x;                  // 0..63
    const int tl    = act_lens[b] - 1;
    const int ul    = label_lens[b];
    const int dfin  = tl + ul;                  // [177, 355]
    const int start = dfin & 3;
    const int niter = dfin >> 2;                // 44..88 composed steps

    const unsigned* combB = comb + (size_t)b * DROWS * ROWU;

    // scalar/prologue loads first, then drain so the stage burst is clean
    float fin_bl = ubit(combB[(size_t)(dfin + 1) * ROWU + ul] << 16);
    float v0, v1;
    prologue(combB, start, l, tl, ul, v0, v1);
    asm volatile("s_waitcnt vmcnt(0)" ::: "memory");

    // ---- stage: niter rows of V -> LDS (1024 B per instr, 16 B/lane) ----
    {
        const char* g = (const char*)(V + (size_t)b * NITMAX * VROWU) + l * 16;
        const int nload = (niter * VROWB + 1023) >> 10;   // <= 110
        for (int i = 0; i < nload; ++i) {
            __builtin_amdgcn_global_load_lds(
                (const __attribute__((address_space(1))) void*)(g + (size_t)i * 1024),
                (__attribute__((address_space(3))) void*)(sV + (size_t)i * 1024), 16, 0, 0);
        }
        asm volatile("s_waitcnt vmcnt(0)" ::: "memory");
    }

    // ---- serial quad-step chain, LDS-only operands ----
    float rf0 = NEGF, rf1 = NEGF;
    const char* Lc = sV + 8 * l;
    uv2 q0[4], q1[4], q2[4];
    #pragma unroll
    for (int j = 0; j < 4; ++j) {               // prime rows 0..3
        const char* p = Lc + (size_t)j * VROWB;
        q0[j] = *(const uv2*)(p);
        q1[j] = *(const uv2*)(p + 416);
        q2[j] = *(const uv2*)(p + 832);
    }
    const int ngroups = (niter + 3) >> 2;       // 11..22 groups of 4
    for (int g4 = 0; g4 < ngroups; ++g4) {
        const int it0 = g4 * 4;
        #pragma unroll
        for (int J = 0; J < 4; ++J) {           // static slot index (rule #20)
            const int it = it0 + J;
            uv2 a0 = q0[J], a1 = q1[J], a2 = q2[J];
            float V0a = ubit(a0.x << 16), V1a = ubit(a0.x & 0xFFFF0000u);
            float V0b = ubit(a0.y << 16), V1b = ubit(a0.y & 0xFFFF0000u);
            float V2a = ubit(a1.x << 16), V3a = ubit(a1.x & 0xFFFF0000u);
            float V2b = ubit(a1.y << 16), V3b = ubit(a1.y & 0xFFFF0000u);
            float V4a = ubit(a2.x << 16), V4b = ubit(a2.y << 16);
            float s1 = lane_shr1(v1);           // alpha[2l-1]
            float s0 = lane_shr1(v0);           // alpha[2l-2]
            float s3 = lane_shr1(s1);           // alpha[2l-3]
            float s2 = lane_shr1(s0);           // alpha[2l-4]
            float nA = lse5(v0 + V0a, s1 + V1a, s0 + V2a, s3 + V3a, s2 + V4a);
            float nB = lse5(v1 + V0b, v0 + V1b, s1 + V2b, s0 + V3b, s3 + V4b);
            if (it == niter - 1) { rf0 = nA; rf1 = nB; }   // capture at dfin
            v0 = nA; v1 = nB;
            int rr = it + 4; rr = rr < niter ? rr : niter - 1;   // staged-safe
            const char* p = Lc + (size_t)rr * VROWB;
            q0[J] = *(const uv2*)(p);
            q1[J] = *(const uv2*)(p + 416);
            q2[J] = *(const uv2*)(p + 832);
        }
    }

    float res = (ul & 1) ? rf1 : rf0;           // alpha[tl,ul] in lane ul>>1
    if (l == (ul >> 1)) {
        loglike[b] = LN2 * (res + fin_bl);
        __threadfence();                        // publish before signaling
        int old = atomicAdd(counter, 1);        // device-scope
        if (old == B_DIM - 1) {                 // last block finalizes
            __threadfence();
            float s = 0.0f;
            #pragma unroll
            for (int i = 0; i < B_DIM; ++i)
                s += __hip_atomic_load(&loglike[i], __ATOMIC_RELAXED,
                                       __HIP_MEMORY_SCOPE_AGENT);
            out[0] = -s / (float)B_DIM;
        }
    }
}

extern "C" void kernel_launch(void* const* d_in, const int* in_sizes, int n_in,
                              void* d_out, int out_size, void* d_ws, size_t ws_size,
                              hipStream_t stream) {
    const float* acts       = (const float*)d_in[0];
    const int*   labels     = (const int*)d_in[1];
    const int*   act_lens   = (const int*)d_in[2];
    const int*   label_lens = (const int*)d_in[3];

    unsigned* comb    = (unsigned*)d_ws;                          // 1.47 MB
    unsigned* V       = comb + (size_t)B_DIM * DROWS * ROWU;      // 0.90 MB
    float*    loglike = (float*)(V + (size_t)B_DIM * NITMAX * VROWU);
    int*      counter = (int*)(loglike + B_DIM);

    int nrows   = B_DIM * T_DIM * U1_DIM;                         // 206,848
    int nblocks = (nrows + 7) / 8;

    // >64KB dynamic LDS (112,640 B; CU has 160 KB) — capture-safe (R12 proven)
    hipFuncSetAttribute(reinterpret_cast<const void*>(dp3_kernel),
                        hipFuncAttributeMaxDynamicSharedMemorySize, LDS_BYTES);

    lsm_kernel<<<nblocks, 256, 0, stream>>>(acts, labels, act_lens, label_lens,
                                            (unsigned short*)comb, counter, nrows);
    int vwaves = B_DIM * NITMAX;                                  // 704 waves
    v4c_kernel<<<(vwaves + 3) / 4, 256, 0, stream>>>(comb, act_lens, label_lens, V);
    dp3_kernel<<<B_DIM, 64, LDS_BYTES, stream>>>(comb, V, act_lens, label_lens,
                                                 loglike, counter, (float*)d_out);
}